// Round 7
// baseline (251.846 us; speedup 1.0000x reference)
//
#include <hip/hip_runtime.h>

#define BSEG   16384
#define NPART  256          // elem-loss partial slots, each on its own 64B line
#define RMAX   64           // max replicas of the segment arrays

// ws layout: [R * 2*BSEG floats: replicas (seg_in|seg_tg)] [NPART*8 doubles
// elem_part, line-strided] [1 double acc]
static inline size_t ws_need(int R) {
    return (size_t)R * 2 * BSEG * 4 + (size_t)NPART * 8 * 8 + 8;
}

__global__ __launch_bounds__(256, 4) void main_pass(
        const float* __restrict__ in, const float* __restrict__ tg,
        const int* __restrict__ batch,
        float* __restrict__ rep, double* __restrict__ elem_part,
        int n, int rmask)
{
    const int tid  = blockIdx.x * blockDim.x + threadIdx.x;
    const int lane = threadIdx.x & 63;
    float* seg_in = rep + (size_t)(blockIdx.x & rmask) * (2 * BSEG);
    float* seg_tg = seg_in + BSEG;

    const long long i0 = (long long)tid * 8;
    float elem = 0.0f;
    int   cur  = -1;          // dead lanes: id -1, zero sums (scan-safe)
    float si = 0.0f, st = 0.0f;

    if (i0 < n) {  // N divisible by 8 => live threads have full chunks
        const float4* in4 = reinterpret_cast<const float4*>(in + i0);
        const float4* tg4 = reinterpret_cast<const float4*>(tg + i0);
        const int4*   b4  = reinterpret_cast<const int4*>(batch + i0);

        float4 a0 = in4[0], a1 = in4[1];
        float4 t0 = tg4[0], t1 = tg4[1];
        int4   c0 = b4[0],  c1 = b4[1];

        float vi[8] = {a0.x, a0.y, a0.z, a0.w, a1.x, a1.y, a1.z, a1.w};
        float vt[8] = {t0.x, t0.y, t0.z, t0.w, t1.x, t1.y, t1.z, t1.w};
        int   vb[8] = {c0.x, c0.y, c0.z, c0.w, c1.x, c1.y, c1.z, c1.w};

        cur = vb[0];
        #pragma unroll
        for (int j = 0; j < 8; ++j) {
            float x = vi[j], y = vt[j];
            float d = fabsf(x) - fabsf(y);
            elem = fmaf(d, d, elem);
            int b = vb[j];
            if (b != cur) {           // interior boundary (~0.65% of threads)
                atomicAdd(seg_in + cur, si);
                atomicAdd(seg_tg + cur, st);
                cur = b; si = 0.0f; st = 0.0f;
            }
            si += x; st += y;
        }
    }

    // --- wave segmented scan; sorted ids => segment test is id equality ---
    #pragma unroll
    for (int d = 1; d < 64; d <<= 1) {
        float o1 = __shfl_up(si, d);
        float o2 = __shfl_up(st, d);
        int  oid = __shfl_up(cur, d);
        if (lane >= d && oid == cur) { si += o1; st += o2; }
    }
    const int  nextId = __shfl_down(cur, 1);
    const bool isTail = (lane == 63) || (nextId != cur);
    if (isTail && cur >= 0) {
        atomicAdd(seg_in + cur, si);
        atomicAdd(seg_tg + cur, st);
    }

    // --- block-reduce elementwise loss -> line-padded partial slots ---
    #pragma unroll
    for (int off = 32; off; off >>= 1) elem += __shfl_xor(elem, off);
    __shared__ float wsum[4];
    int wid = threadIdx.x >> 6;
    if (lane == 0) wsum[wid] = elem;
    __syncthreads();
    if (threadIdx.x == 0) {
        float s = wsum[0] + wsum[1] + wsum[2] + wsum[3];
        atomicAdd(elem_part + (size_t)(blockIdx.x & (NPART - 1)) * 8, (double)s);
    }
}

// Fold replicas, square, reduce. 64 blocks x 256 threads; thread s owns segment s.
__global__ __launch_bounds__(256) void seg_reduce(
        const float* __restrict__ rep, int R, double* __restrict__ acc)
{
    const int s = blockIdx.x * 256 + threadIdx.x;    // 0..BSEG-1
    float si = 0.0f, st = 0.0f;
    for (int r = 0; r < R; ++r) {
        si += rep[(size_t)r * 2 * BSEG + s];
        st += rep[(size_t)r * 2 * BSEG + BSEG + s];
    }
    float d = si * si - st * st;                      // f32 like the reference
    double a = (double)d * (double)d;
    #pragma unroll
    for (int off = 32; off; off >>= 1) a += __shfl_xor(a, off);
    __shared__ double wsum[4];
    int lane = threadIdx.x & 63, wid = threadIdx.x >> 6;
    if (lane == 0) wsum[wid] = a;
    __syncthreads();
    if (threadIdx.x == 0)
        atomicAdd(acc, wsum[0] + wsum[1] + wsum[2] + wsum[3]);
}

__global__ __launch_bounds__(256) void final_combine(
        const double* __restrict__ elem_part, const double* __restrict__ acc,
        float* __restrict__ out)
{
    double v = elem_part[(size_t)threadIdx.x * 8];
    #pragma unroll
    for (int off = 32; off; off >>= 1) v += __shfl_xor(v, off);
    __shared__ double wsum[4];
    int lane = threadIdx.x & 63, wid = threadIdx.x >> 6;
    if (lane == 0) wsum[wid] = v;
    __syncthreads();
    if (threadIdx.x == 0)
        out[0] = (float)(wsum[0] + wsum[1] + wsum[2] + wsum[3] + *acc);
}

extern "C" void kernel_launch(void* const* d_in, const int* in_sizes, int n_in,
                              void* d_out, int out_size, void* d_ws, size_t ws_size,
                              hipStream_t stream) {
    const float* in    = (const float*)d_in[0];
    const float* tg    = (const float*)d_in[1];
    const int*   batch = (const int*)d_in[2];
    const int n = in_sizes[0];

    int R = 1;
    while (R < RMAX && ws_need(R * 2) <= ws_size) R *= 2;

    float*  rep       = (float*)d_ws;
    double* elem_part = (double*)(rep + (size_t)R * 2 * BSEG);
    double* acc       = elem_part + (size_t)NPART * 8;
    float*  out       = (float*)d_out;

    hipMemsetAsync(d_ws, 0, ws_need(R), stream);

    const int nthreads = n / 8;
    const int blocks   = (nthreads + 255) / 256;
    main_pass<<<blocks, 256, 0, stream>>>(in, tg, batch, rep, elem_part, n, R - 1);

    seg_reduce<<<BSEG / 256, 256, 0, stream>>>(rep, R, acc);
    final_combine<<<1, 256, 0, stream>>>(elem_part, acc, out);
}

// Round 10
// 232.868 us; speedup vs baseline: 1.0815x; 1.0815x over previous
//
#include <hip/hip_runtime.h>

#define BSEG   16384
#define NPART  256
#define LRANGE 64     // LDS privatization window: ids covered by one block
// ws layout (same as R5, proven to fit): seg_in[BSEG] f32, seg_tg[BSEG] f32,
// elem_part[NPART] f64
#define WS_BYTES (2 * BSEG * 4 + NPART * 8)

__global__ __launch_bounds__(256) void main_pass(
        const float* __restrict__ in, const float* __restrict__ tg,
        const int* __restrict__ batch,
        float* __restrict__ seg_in, float* __restrict__ seg_tg,
        double* __restrict__ elem_part, int n)
{
    __shared__ float lsi[LRANGE], lst[LRANGE];
    __shared__ int   firstIdSh;
    __shared__ float wsum[4];

    const int tid  = blockIdx.x * blockDim.x + threadIdx.x;
    const int lane = threadIdx.x & 63;
    const long long i0 = (long long)tid * 8;
    const bool live = (i0 < n);           // N divisible by 8 => full chunks

    float4 a0, a1, t0, t1; int4 c0, c1;
    if (live) {
        const float4* in4 = reinterpret_cast<const float4*>(in + i0);
        const float4* tg4 = reinterpret_cast<const float4*>(tg + i0);
        const int4*   b4  = reinterpret_cast<const int4*>(batch + i0);
        a0 = in4[0]; a1 = in4[1];
        t0 = tg4[0]; t1 = tg4[1];
        c0 = b4[0];  c1 = b4[1];
    }

    // zero LDS table; publish block's first segment id (thread 0 always live)
    for (int k = threadIdx.x; k < LRANGE; k += 256) { lsi[k] = 0.0f; lst[k] = 0.0f; }
    if (threadIdx.x == 0) firstIdSh = c0.x;
    __syncthreads();
    const int firstId = firstIdSh;        // block-uniform; block ids are >= this

    float elem = 0.0f;
    int   cur  = -1;                      // dead lanes: sentinel, zero sums
    float si = 0.0f, st = 0.0f;

    if (live) {
        float vi[8] = {a0.x, a0.y, a0.z, a0.w, a1.x, a1.y, a1.z, a1.w};
        float vt[8] = {t0.x, t0.y, t0.z, t0.w, t1.x, t1.y, t1.z, t1.w};
        int   vb[8] = {c0.x, c0.y, c0.z, c0.w, c1.x, c1.y, c1.z, c1.w};
        cur = vb[0];
        #pragma unroll
        for (int j = 0; j < 8; ++j) {
            float x = vi[j], y = vt[j];
            float d = fabsf(x) - fabsf(y);
            elem = fmaf(d, d, elem);
            int b = vb[j];
            if (b != cur) {               // interior boundary (~0.65% of threads)
                int off = cur - firstId;  // >= 0 by sortedness
                if (off < LRANGE) { atomicAdd(&lsi[off], si); atomicAdd(&lst[off], st); }
                else { atomicAdd(seg_in + cur, si); atomicAdd(seg_tg + cur, st); }
                cur = b; si = 0.0f; st = 0.0f;
            }
            si += x; st += y;
        }
    }

    // --- wave segmented scan; sorted ids => segment test is id equality ---
    #pragma unroll
    for (int d = 1; d < 64; d <<= 1) {
        float o1 = __shfl_up(si, d);
        float o2 = __shfl_up(st, d);
        int  oid = __shfl_up(cur, d);
        if (lane >= d && oid == cur) { si += o1; st += o2; }
    }
    const int  nextId = __shfl_down(cur, 1);
    const bool isTail = (lane == 63) || (nextId != cur);
    if (isTail && cur >= 0) {
        int off = cur - firstId;
        if (off < LRANGE) { atomicAdd(&lsi[off], si); atomicAdd(&lst[off], st); }
        else { atomicAdd(seg_in + cur, si); atomicAdd(seg_tg + cur, st); }
    }

    __syncthreads();
    // --- flush LDS table: ~2-3 nonzero entries per block ---
    if (threadIdx.x < LRANGE) {
        float a = lsi[threadIdx.x], b = lst[threadIdx.x];
        if (a != 0.0f || b != 0.0f) {     // skipping zero adds is identity-safe
            atomicAdd(seg_in + firstId + threadIdx.x, a);
            atomicAdd(seg_tg + firstId + threadIdx.x, b);
        }
    }

    // --- block-reduce elementwise loss -> 256 partial slots ---
    #pragma unroll
    for (int off = 32; off; off >>= 1) elem += __shfl_xor(elem, off);
    int wid = threadIdx.x >> 6;
    if (lane == 0) wsum[wid] = elem;
    __syncthreads();
    if (threadIdx.x == 0) {
        float s = wsum[0] + wsum[1] + wsum[2] + wsum[3];
        atomicAdd(elem_part + (blockIdx.x & (NPART - 1)), (double)s);
    }
}

__global__ __launch_bounds__(1024) void finalize_kernel(
        const float* __restrict__ seg_in, const float* __restrict__ seg_tg,
        const double* __restrict__ elem_part, float* __restrict__ out)
{
    const float4* s4 = (const float4*)seg_in;
    const float4* g4 = (const float4*)seg_tg;
    double acc = 0.0;
    for (int i = threadIdx.x; i < BSEG / 4; i += 1024) {
        float4 a = s4[i], b = g4[i];
        float d0 = a.x * a.x - b.x * b.x;
        float d1 = a.y * a.y - b.y * b.y;
        float d2 = a.z * a.z - b.z * b.z;
        float d3 = a.w * a.w - b.w * b.w;
        acc += (double)d0 * d0 + (double)d1 * d1 + (double)d2 * d2 + (double)d3 * d3;
    }
    if (threadIdx.x < NPART) acc += elem_part[threadIdx.x];
    #pragma unroll
    for (int off = 32; off; off >>= 1) acc += __shfl_xor(acc, off);
    __shared__ double wsum[16];
    int lane = threadIdx.x & 63, wid = threadIdx.x >> 6;
    if (lane == 0) wsum[wid] = acc;
    __syncthreads();
    if (threadIdx.x == 0) {
        double t = 0.0;
        #pragma unroll
        for (int w = 0; w < 16; ++w) t += wsum[w];
        out[0] = (float)t;
    }
}

extern "C" void kernel_launch(void* const* d_in, const int* in_sizes, int n_in,
                              void* d_out, int out_size, void* d_ws, size_t ws_size,
                              hipStream_t stream) {
    const float* in    = (const float*)d_in[0];
    const float* tg    = (const float*)d_in[1];
    const int*   batch = (const int*)d_in[2];
    const int n = in_sizes[0];

    float*  seg_in    = (float*)d_ws;
    float*  seg_tg    = seg_in + BSEG;
    double* elem_part = (double*)(seg_in + 2 * BSEG);
    float*  out       = (float*)d_out;

    hipMemsetAsync(d_ws, 0, WS_BYTES, stream);

    const int nthreads = n / 8;
    const int blocks   = (nthreads + 255) / 256;
    main_pass<<<blocks, 256, 0, stream>>>(in, tg, batch, seg_in, seg_tg, elem_part, n);

    finalize_kernel<<<1, 1024, 0, stream>>>(seg_in, seg_tg, elem_part, out);
}

// Round 13
// 231.252 us; speedup vs baseline: 1.0891x; 1.0070x over previous
//
#include <hip/hip_runtime.h>

#define BSEG   16384
#define NPART  256
#define CHUNK  16
// ws layout (proven to fit): seg_in[BSEG] f32, seg_tg[BSEG] f32, elem_part[NPART] f64
#define WS_BYTES (2 * BSEG * 4 + NPART * 8)

__global__ __launch_bounds__(256, 4) void main_pass(
        const float* __restrict__ in, const float* __restrict__ tg,
        const int* __restrict__ batch,
        float* __restrict__ seg_in, float* __restrict__ seg_tg,
        double* __restrict__ elem_part, int n)
{
    const int tid  = blockIdx.x * blockDim.x + threadIdx.x;
    const int lane = threadIdx.x & 63;
    const long long i0 = (long long)tid * CHUNK;
    const bool live = (i0 < n);          // N divisible by 16 => full chunks

    // ---- all 12 loads issued up-front, no consumer in between ----
    float4 a[4], t[4]; int4 c[4];
    if (live) {
        const float4* in4 = reinterpret_cast<const float4*>(in + i0);
        const float4* tg4 = reinterpret_cast<const float4*>(tg + i0);
        const int4*   b4  = reinterpret_cast<const int4*>(batch + i0);
        #pragma unroll
        for (int q = 0; q < 4; ++q) a[q] = in4[q];
        #pragma unroll
        for (int q = 0; q < 4; ++q) t[q] = tg4[q];
        #pragma unroll
        for (int q = 0; q < 4; ++q) c[q] = b4[q];
    }

    float elem = 0.0f;
    int   cur  = -1;                     // dead lanes: sentinel, zero sums
    float si = 0.0f, st = 0.0f;

    if (live) {
        float vi[CHUNK], vt[CHUNK]; int vb[CHUNK];
        #pragma unroll
        for (int q = 0; q < 4; ++q) {
            vi[4*q+0] = a[q].x; vi[4*q+1] = a[q].y; vi[4*q+2] = a[q].z; vi[4*q+3] = a[q].w;
            vt[4*q+0] = t[q].x; vt[4*q+1] = t[q].y; vt[4*q+2] = t[q].z; vt[4*q+3] = t[q].w;
            vb[4*q+0] = c[q].x; vb[4*q+1] = c[q].y; vb[4*q+2] = c[q].z; vb[4*q+3] = c[q].w;
        }
        cur = vb[0];
        #pragma unroll
        for (int j = 0; j < CHUNK; ++j) {
            float x = vi[j], y = vt[j];
            float d = fabsf(x) - fabsf(y);
            elem = fmaf(d, d, elem);
            int b = vb[j];
            if (b != cur) {              // interior boundary (~1.3% of threads)
                atomicAdd(seg_in + cur, si);
                atomicAdd(seg_tg + cur, st);
                cur = b; si = 0.0f; st = 0.0f;
            }
            si += x; st += y;
        }
    }

    // --- wave segmented scan; sorted ids => segment test is id equality ---
    #pragma unroll
    for (int d = 1; d < 64; d <<= 1) {
        float o1 = __shfl_up(si, d);
        float o2 = __shfl_up(st, d);
        int  oid = __shfl_up(cur, d);
        if (lane >= d && oid == cur) { si += o1; st += o2; }
    }
    const int  nextId = __shfl_down(cur, 1);
    const bool isTail = (lane == 63) || (nextId != cur);
    if (isTail && cur >= 0) {
        atomicAdd(seg_in + cur, si);
        atomicAdd(seg_tg + cur, st);
    }

    // --- block-reduce elementwise loss -> 256 partial slots ---
    #pragma unroll
    for (int off = 32; off; off >>= 1) elem += __shfl_xor(elem, off);
    __shared__ float wsum[4];
    int wid = threadIdx.x >> 6;
    if (lane == 0) wsum[wid] = elem;
    __syncthreads();
    if (threadIdx.x == 0) {
        float s = wsum[0] + wsum[1] + wsum[2] + wsum[3];
        atomicAdd(elem_part + (blockIdx.x & (NPART - 1)), (double)s);
    }
}

__global__ __launch_bounds__(1024) void finalize_kernel(
        const float* __restrict__ seg_in, const float* __restrict__ seg_tg,
        const double* __restrict__ elem_part, float* __restrict__ out)
{
    const float4* s4 = (const float4*)seg_in;
    const float4* g4 = (const float4*)seg_tg;
    double acc = 0.0;
    for (int i = threadIdx.x; i < BSEG / 4; i += 1024) {
        float4 a = s4[i], b = g4[i];
        float d0 = a.x * a.x - b.x * b.x;
        float d1 = a.y * a.y - b.y * b.y;
        float d2 = a.z * a.z - b.z * b.z;
        float d3 = a.w * a.w - b.w * b.w;
        acc += (double)d0 * d0 + (double)d1 * d1 + (double)d2 * d2 + (double)d3 * d3;
    }
    if (threadIdx.x < NPART) acc += elem_part[threadIdx.x];
    #pragma unroll
    for (int off = 32; off; off >>= 1) acc += __shfl_xor(acc, off);
    __shared__ double wsum[16];
    int lane = threadIdx.x & 63, wid = threadIdx.x >> 6;
    if (lane == 0) wsum[wid] = acc;
    __syncthreads();
    if (threadIdx.x == 0) {
        double t = 0.0;
        #pragma unroll
        for (int w = 0; w < 16; ++w) t += wsum[w];
        out[0] = (float)t;
    }
}

extern "C" void kernel_launch(void* const* d_in, const int* in_sizes, int n_in,
                              void* d_out, int out_size, void* d_ws, size_t ws_size,
                              hipStream_t stream) {
    const float* in    = (const float*)d_in[0];
    const float* tg    = (const float*)d_in[1];
    const int*   batch = (const int*)d_in[2];
    const int n = in_sizes[0];

    float*  seg_in    = (float*)d_ws;
    float*  seg_tg    = seg_in + BSEG;
    double* elem_part = (double*)(seg_in + 2 * BSEG);
    float*  out       = (float*)d_out;

    hipMemsetAsync(d_ws, 0, WS_BYTES, stream);

    const int nthreads = n / CHUNK;                   // N divisible by 16
    const int blocks   = (nthreads + 255) / 256;
    main_pass<<<blocks, 256, 0, stream>>>(in, tg, batch, seg_in, seg_tg, elem_part, n);

    finalize_kernel<<<1, 1024, 0, stream>>>(seg_in, seg_tg, elem_part, out);
}